// Round 1
// 303.104 us; speedup vs baseline: 1.0562x; 1.0562x over previous
//
#include <hip/hip_runtime.h>
#include <math.h>

#define BETA 5.5f
#define NC 1000
#define NM 51
#define ND 1024

typedef float nt_float4 __attribute__((ext_vector_type(4)));

__device__ __forceinline__ float wave_reduce_sum(float v) {
#pragma unroll
    for (int off = 32; off >= 1; off >>= 1) v += __shfl_xor(v, off, 64);
    return v;
}

__device__ __forceinline__ float block_reduce_sum(float v, float* red, int w, int lane) {
    v = wave_reduce_sum(v);
    __syncthreads();               // protect red from previous use
    if (lane == 0) red[w] = v;
    __syncthreads();
    return red[0] + red[1] + red[2] + red[3];
}

// Kernel 1: partial column sums of global_bias (C x D) -> qpart[40][D].
// 40 blocks x 256 threads; each block sums 25 rows over the full D (float4).
// Replaces the old 64-block/128-thread latency-bound version (125-deep serial chain).
__global__ __launch_bounds__(256) void colsum_part(const float* __restrict__ gb,
                                                   float* __restrict__ qpart) {
    const int t = threadIdx.x;
    const float4* p = (const float4*)(gb + (size_t)blockIdx.x * 25 * ND) + t;
    float4 s = make_float4(0.f, 0.f, 0.f, 0.f);
#pragma unroll
    for (int c = 0; c < 25; ++c) {
        float4 v = p[c * (ND / 4)];
        s.x += v.x; s.y += v.y; s.z += v.z; s.w += v.w;
    }
    ((float4*)qpart)[blockIdx.x * (ND / 4) + t] = s;
}

// Kernel 2: qn = l2norm(img + colsum/NC). One block; writes the final normalized
// query so dualmem_main never recomputes it (was 32KB reads + reduce per wave x 2000 blocks).
__global__ __launch_bounds__(256) void qnorm_kernel(const float* __restrict__ img,
                                                    const float* __restrict__ qpart,
                                                    float* __restrict__ qn) {
    __shared__ float red[8];
    const int t = threadIdx.x, w = t >> 6, lane = t & 63;
    float4 s = make_float4(0.f, 0.f, 0.f, 0.f);
#pragma unroll
    for (int p = 0; p < 40; ++p) {
        float4 v = ((const float4*)qpart)[p * (ND / 4) + t];
        s.x += v.x; s.y += v.y; s.z += v.z; s.w += v.w;
    }
    float4 iv = ((const float4*)img)[t];
    float4 q;
    q.x = iv.x + s.x * (1.f / NC);
    q.y = iv.y + s.y * (1.f / NC);
    q.z = iv.z + s.z * (1.f / NC);
    q.w = iv.w + s.w * (1.f / NC);
    float ssq = block_reduce_sum(q.x * q.x + q.y * q.y + q.z * q.z + q.w * q.w, red, w, lane);
    float r = rsqrtf(ssq);
    float4 o = make_float4(q.x * r, q.y * r, q.z * r, q.w * r);
    ((float4*)qn)[t] = o;
}

// Kernel 3: 2 blocks per class (grid=2000). Block handles rows ww, ww+8, ...
// where ww = (half*4 + wave). Row loop is software-pipelined (double-buffered
// cur/nxt registers) so next row's 4KB of HBM loads are in flight during the
// current row's shuffle-reduce chain.
__global__ __launch_bounds__(256) void dualmem_main(
    const float* __restrict__ mem,     // (C,50,D)
    const float* __restrict__ fixedg,  // (C,1,D)
    const float* __restrict__ qn_g,    // (D) normalized query
    const float* __restrict__ gbk,     // (C,D)
    const float* __restrict__ gbv,     // (C,D)
    float* __restrict__ accpart)       // (2000,D)
{
    __shared__ float lds_acc[4 * ND];  // 16 KB per-wave partials

    const int c = blockIdx.x >> 1;
    const int half = blockIdx.x & 1;
    const int t = threadIdx.x;
    const int w = t >> 6;
    const int lane = t & 63;
    const int ww = half * 4 + w;       // global wave id within class, 0..7

    // ---- per-wave copies: normalized q + per-class biases ----
    float4 qn[4], bk[4], bv[4], acc[4];
    const float* bkp = gbk + (size_t)c * ND;
    const float* bvp = gbv + (size_t)c * ND;
#pragma unroll
    for (int j = 0; j < 4; ++j) {
        qn[j] = ((const float4*)qn_g)[j * 64 + lane];
        bk[j] = ((const float4*)bkp)[j * 64 + lane];
        bv[j] = ((const float4*)bvp)[j * 64 + lane];
        acc[j] = make_float4(0.f, 0.f, 0.f, 0.f);
    }

    // ---- software-pipelined main loop: rows ww, ww+8, ... ----
    nt_float4 cur[4], nxt[4];
    {
        const nt_float4* r = (ww < 50) ? (const nt_float4*)(mem + ((size_t)c * 50 + ww) * ND)
                                       : (const nt_float4*)(fixedg + (size_t)c * ND);
#pragma unroll
        for (int j = 0; j < 4; ++j) cur[j] = __builtin_nontemporal_load(&r[j * 64 + lane]);
    }

    for (int m = ww; m < NM; m += 8) {
        const int mn = m + 8;
        if (mn < NM) {  // prefetch next row while we reduce this one
            const nt_float4* r = (mn < 50) ? (const nt_float4*)(mem + ((size_t)c * 50 + mn) * ND)
                                           : (const nt_float4*)(fixedg + (size_t)c * ND);
#pragma unroll
            for (int j = 0; j < 4; ++j) nxt[j] = __builtin_nontemporal_load(&r[j * 64 + lane]);
        }

        float sm = 0.f, ssqK = 0.f, dotK = 0.f, ssqV = 0.f;
#pragma unroll
        for (int j = 0; j < 4; ++j) {
            nt_float4 v = cur[j];
            sm += v.x + v.y + v.z + v.w;
            float kx = v.x + bk[j].x, ky = v.y + bk[j].y, kz = v.z + bk[j].z, kw = v.w + bk[j].w;
            ssqK += kx * kx + ky * ky + kz * kz + kw * kw;
            dotK += qn[j].x * kx + qn[j].y * ky + qn[j].z * kz + qn[j].w * kw;
            float vx = v.x + bv[j].x, vy = v.y + bv[j].y, vz = v.z + bv[j].z, vw = v.w + bv[j].w;
            ssqV += vx * vx + vy * vy + vz * vz + vw * vw;
        }
        sm   = wave_reduce_sum(sm);
        ssqK = wave_reduce_sum(ssqK);
        dotK = wave_reduce_sum(dotK);
        ssqV = wave_reduce_sum(ssqV);
        if (sm != 0.f) {  // non-empty slot
            float simv = expf(-BETA * (1.f - dotK * rsqrtf(ssqK)));
            float wt = simv * rsqrtf(ssqV);
#pragma unroll
            for (int j = 0; j < 4; ++j) {
                acc[j].x += wt * (cur[j].x + bv[j].x);
                acc[j].y += wt * (cur[j].y + bv[j].y);
                acc[j].z += wt * (cur[j].z + bv[j].z);
                acc[j].w += wt * (cur[j].w + bv[j].w);
            }
        }
#pragma unroll
        for (int j = 0; j < 4; ++j) cur[j] = nxt[j];
    }

    // ---- combine 4 waves through LDS, store 4KB block partial ----
#pragma unroll
    for (int j = 0; j < 4; ++j)
        ((float4*)lds_acc)[w * 256 + j * 64 + lane] = acc[j];
    __syncthreads();

    float4 a = make_float4(0.f, 0.f, 0.f, 0.f);
#pragma unroll
    for (int wv = 0; wv < 4; ++wv) {
        float4 p = ((float4*)lds_acc)[wv * 256 + t];
        a.x += p.x; a.y += p.y; a.z += p.z; a.w += p.w;
    }
    ((float4*)(accpart + (size_t)blockIdx.x * ND))[t] = a;
}

// Kernel 4: per class, sum 2 partials, l2norm, +ffn, l2norm, logit.
__global__ __launch_bounds__(256) void finalize_kernel(
    const float* __restrict__ img,
    const float* __restrict__ accpart,  // (2000,D)
    const float* __restrict__ ffn,      // (C,D)
    const float* __restrict__ lsp,      // scalar
    float* __restrict__ logits)         // (C)
{
    __shared__ float red[8];
    const int c = blockIdx.x;
    const int t = threadIdx.x;
    const int w = t >> 6;
    const int lane = t & 63;

    float4 a0 = ((const float4*)(accpart + (size_t)(2 * c) * ND))[t];
    float4 a1 = ((const float4*)(accpart + (size_t)(2 * c + 1) * ND))[t];
    float4 a;
    a.x = a0.x + a1.x; a.y = a0.y + a1.y; a.z = a0.z + a1.z; a.w = a0.w + a1.w;

    float ssqA = block_reduce_sum(a.x * a.x + a.y * a.y + a.z * a.z + a.w * a.w, red, w, lane);
    float arn = rsqrtf(ssqA);
    float4 fv = ((const float4*)(ffn + (size_t)c * ND))[t];
    a.x = a.x * arn + fv.x;
    a.y = a.y * arn + fv.y;
    a.z = a.z * arn + fv.z;
    a.w = a.w * arn + fv.w;
    float ssqB = block_reduce_sum(a.x * a.x + a.y * a.y + a.z * a.z + a.w * a.w, red, w, lane);
    float brn = rsqrtf(ssqB);

    float4 iv = ((const float4*)img)[t];
    float dp = a.x * iv.x + a.y * iv.y + a.z * iv.z + a.w * iv.w;
    dp = block_reduce_sum(dp, red, w, lane);

    if (t == 0) logits[c] = expf(lsp[0]) * dp * brn;
}

// Kernel 5: softmax over 1000 logits
__global__ __launch_bounds__(256) void softmax_kernel(const float* __restrict__ logits,
                                                      float* __restrict__ out) {
    __shared__ float red[8];
    int t = threadIdx.x, w = t >> 6, lane = t & 63;
    float l[4];
#pragma unroll
    for (int i = 0; i < 4; ++i) {
        int idx = t * 4 + i;
        l[i] = (idx < NC) ? logits[idx] : -3.402823466e+38f;
    }
    float mx = fmaxf(fmaxf(l[0], l[1]), fmaxf(l[2], l[3]));
#pragma unroll
    for (int off = 32; off >= 1; off >>= 1) mx = fmaxf(mx, __shfl_xor(mx, off, 64));
    __syncthreads();
    if (lane == 0) red[w] = mx;
    __syncthreads();
    mx = fmaxf(fmaxf(red[0], red[1]), fmaxf(red[2], red[3]));
    __syncthreads();

    float e[4], s = 0.f;
#pragma unroll
    for (int i = 0; i < 4; ++i) {
        int idx = t * 4 + i;
        e[i] = (idx < NC) ? expf(l[i] - mx) : 0.f;
        s += e[i];
    }
    s = block_reduce_sum(s, red, w, lane);
    float inv = 1.f / s;
#pragma unroll
    for (int i = 0; i < 4; ++i) {
        int idx = t * 4 + i;
        if (idx < NC) out[idx] = e[i] * inv;
    }
}

extern "C" void kernel_launch(void* const* d_in, const int* in_sizes, int n_in,
                              void* d_out, int out_size, void* d_ws, size_t ws_size,
                              hipStream_t stream) {
    const float* img    = (const float*)d_in[0];  // (1,D)
    const float* mem    = (const float*)d_in[1];  // (C,50,D)
    const float* fixedg = (const float*)d_in[2];  // (C,1,D)
    const float* gb     = (const float*)d_in[3];  // (C,D)
    const float* gbk    = (const float*)d_in[4];  // (C,D)
    const float* gbv    = (const float*)d_in[5];  // (C,D)
    const float* ffn    = (const float*)d_in[6];  // (C,D)
    const float* ls     = (const float*)d_in[7];  // scalar

    float* ws      = (float*)d_ws;
    float* qpart   = ws;                   // 40*1024
    float* qn      = ws + 40 * ND;         // 1024
    float* accpart = ws + 41 * ND;         // 2000*1024
    float* logits  = accpart + 2000 * ND;  // 1000
    float* out     = (float*)d_out;

    colsum_part<<<40, 256, 0, stream>>>(gb, qpart);
    qnorm_kernel<<<1, 256, 0, stream>>>(img, qpart, qn);
    dualmem_main<<<2 * NC, 256, 0, stream>>>(mem, fixedg, qn, gbk, gbv, accpart);
    finalize_kernel<<<NC, 256, 0, stream>>>(img, accpart, ffn, ls, logits);
    softmax_kernel<<<1, 256, 0, stream>>>(logits, out);
}

// Round 2
// 302.747 us; speedup vs baseline: 1.0574x; 1.0012x over previous
//
#include <hip/hip_runtime.h>
#include <math.h>

#define BETA 5.5f
#define NC 1000
#define NM 51
#define ND 1024

typedef float nt_float4 __attribute__((ext_vector_type(4)));

__device__ __forceinline__ float wave_reduce_sum(float v) {
#pragma unroll
    for (int off = 32; off >= 1; off >>= 1) v += __shfl_xor(v, off, 64);
    return v;
}

// 4-wave block reduce (for 256-thread kernels)
__device__ __forceinline__ float block_reduce_sum4(float v, float* red, int w, int lane) {
    v = wave_reduce_sum(v);
    __syncthreads();
    if (lane == 0) red[w] = v;
    __syncthreads();
    return red[0] + red[1] + red[2] + red[3];
}

// 8-wave block reduce (for the 512-thread fused kernel)
__device__ __forceinline__ float block_reduce_sum8(float v, float* red, int w, int lane) {
    v = wave_reduce_sum(v);
    __syncthreads();
    if (lane == 0) red[w] = v;
    __syncthreads();
    return (red[0] + red[1] + red[2] + red[3]) + (red[4] + red[5] + red[6] + red[7]);
}

// Kernel 1: partial column sums of global_bias (C x D) -> qpart[40][D].
__global__ __launch_bounds__(256) void colsum_part(const float* __restrict__ gb,
                                                   float* __restrict__ qpart) {
    const int t = threadIdx.x;
    const float4* p = (const float4*)(gb + (size_t)blockIdx.x * 25 * ND) + t;
    float4 s = make_float4(0.f, 0.f, 0.f, 0.f);
#pragma unroll
    for (int c = 0; c < 25; ++c) {
        float4 v = p[c * (ND / 4)];
        s.x += v.x; s.y += v.y; s.z += v.z; s.w += v.w;
    }
    ((float4*)qpart)[blockIdx.x * (ND / 4) + t] = s;
}

// Kernel 2: qn = l2norm(img + colsum/NC). One block; final normalized query.
__global__ __launch_bounds__(256) void qnorm_kernel(const float* __restrict__ img,
                                                    const float* __restrict__ qpart,
                                                    float* __restrict__ qn) {
    __shared__ float red[8];
    const int t = threadIdx.x, w = t >> 6, lane = t & 63;
    float4 s = make_float4(0.f, 0.f, 0.f, 0.f);
#pragma unroll
    for (int p = 0; p < 40; ++p) {
        float4 v = ((const float4*)qpart)[p * (ND / 4) + t];
        s.x += v.x; s.y += v.y; s.z += v.z; s.w += v.w;
    }
    float4 iv = ((const float4*)img)[t];
    float4 q;
    q.x = iv.x + s.x * (1.f / NC);
    q.y = iv.y + s.y * (1.f / NC);
    q.z = iv.z + s.z * (1.f / NC);
    q.w = iv.w + s.w * (1.f / NC);
    float ssq = block_reduce_sum4(q.x * q.x + q.y * q.y + q.z * q.z + q.w * q.w, red, w, lane);
    float r = rsqrtf(ssq);
    float4 o = make_float4(q.x * r, q.y * r, q.z * r, q.w * r);
    ((float4*)qn)[t] = o;
}

// Kernel 3 (fused main+finalize): one class per 512-thread block (8 waves).
// Wave w handles rows w, w+8, ... (identical FP order per wave as the previous
// 2-blocks-per-class version). Row loop is software-pipelined. After the LDS
// combine, the same block performs l2norm -> +ffn -> l2norm -> img-dot -> logit,
// eliminating the accpart round-trip (16.4 MB) and the finalize launch.
__global__ __launch_bounds__(512) void dualmem_fused(
    const float* __restrict__ mem,     // (C,50,D)
    const float* __restrict__ fixedg,  // (C,1,D)
    const float* __restrict__ qn_g,    // (D) normalized query
    const float* __restrict__ gbk,     // (C,D)
    const float* __restrict__ gbv,     // (C,D)
    const float* __restrict__ ffn,     // (C,D)
    const float* __restrict__ img,     // (1,D)
    const float* __restrict__ lsp,     // scalar
    float* __restrict__ logits)        // (C)
{
    __shared__ float lds_acc[8 * ND];  // 32 KB per-wave partials
    __shared__ float red[8];

    const int c = blockIdx.x;
    const int t = threadIdx.x;
    const int w = t >> 6;
    const int lane = t & 63;

    // ---- per-wave copies: normalized q + per-class biases ----
    float4 qn[4], bk[4], bv[4], acc[4];
    const float* bkp = gbk + (size_t)c * ND;
    const float* bvp = gbv + (size_t)c * ND;
#pragma unroll
    for (int j = 0; j < 4; ++j) {
        qn[j] = ((const float4*)qn_g)[j * 64 + lane];
        bk[j] = ((const float4*)bkp)[j * 64 + lane];
        bv[j] = ((const float4*)bvp)[j * 64 + lane];
        acc[j] = make_float4(0.f, 0.f, 0.f, 0.f);
    }

    // ---- software-pipelined main loop: rows w, w+8, ... ----
    nt_float4 cur[4], nxt[4];
    {
        const nt_float4* r = (w < 50) ? (const nt_float4*)(mem + ((size_t)c * 50 + w) * ND)
                                      : (const nt_float4*)(fixedg + (size_t)c * ND);
#pragma unroll
        for (int j = 0; j < 4; ++j) cur[j] = __builtin_nontemporal_load(&r[j * 64 + lane]);
    }

    for (int m = w; m < NM; m += 8) {
        const int mn = m + 8;
        if (mn < NM) {  // prefetch next row while we reduce this one
            const nt_float4* r = (mn < 50) ? (const nt_float4*)(mem + ((size_t)c * 50 + mn) * ND)
                                           : (const nt_float4*)(fixedg + (size_t)c * ND);
#pragma unroll
            for (int j = 0; j < 4; ++j) nxt[j] = __builtin_nontemporal_load(&r[j * 64 + lane]);
        }

        float sm = 0.f, ssqK = 0.f, dotK = 0.f, ssqV = 0.f;
#pragma unroll
        for (int j = 0; j < 4; ++j) {
            nt_float4 v = cur[j];
            sm += v.x + v.y + v.z + v.w;
            float kx = v.x + bk[j].x, ky = v.y + bk[j].y, kz = v.z + bk[j].z, kw = v.w + bk[j].w;
            ssqK += kx * kx + ky * ky + kz * kz + kw * kw;
            dotK += qn[j].x * kx + qn[j].y * ky + qn[j].z * kz + qn[j].w * kw;
            float vx = v.x + bv[j].x, vy = v.y + bv[j].y, vz = v.z + bv[j].z, vw = v.w + bv[j].w;
            ssqV += vx * vx + vy * vy + vz * vz + vw * vw;
        }
        sm   = wave_reduce_sum(sm);
        ssqK = wave_reduce_sum(ssqK);
        dotK = wave_reduce_sum(dotK);
        ssqV = wave_reduce_sum(ssqV);
        if (sm != 0.f) {  // non-empty slot
            float simv = expf(-BETA * (1.f - dotK * rsqrtf(ssqK)));
            float wt = simv * rsqrtf(ssqV);
#pragma unroll
            for (int j = 0; j < 4; ++j) {
                acc[j].x += wt * (cur[j].x + bv[j].x);
                acc[j].y += wt * (cur[j].y + bv[j].y);
                acc[j].z += wt * (cur[j].z + bv[j].z);
                acc[j].w += wt * (cur[j].w + bv[j].w);
            }
        }
#pragma unroll
        for (int j = 0; j < 4; ++j) cur[j] = nxt[j];
    }

    // ---- combine 8 waves through LDS ----
#pragma unroll
    for (int j = 0; j < 4; ++j)
        ((float4*)lds_acc)[w * 256 + j * 64 + lane] = acc[j];
    __syncthreads();

    // each of the 512 threads owns one float2 slice (1024 floats total)
    float2 s0 = make_float2(0.f, 0.f), s1 = make_float2(0.f, 0.f);
#pragma unroll
    for (int wv = 0; wv < 4; ++wv) {
        float2 p = ((const float2*)lds_acc)[wv * 512 + t];
        s0.x += p.x; s0.y += p.y;
    }
#pragma unroll
    for (int wv = 4; wv < 8; ++wv) {
        float2 p = ((const float2*)lds_acc)[wv * 512 + t];
        s1.x += p.x; s1.y += p.y;
    }
    float2 a = make_float2(s0.x + s1.x, s0.y + s1.y);

    // ---- finalize: l2norm -> +ffn -> l2norm -> logit ----
    float ssqA = block_reduce_sum8(a.x * a.x + a.y * a.y, red, w, lane);
    float arn = rsqrtf(ssqA);
    float2 fv = ((const float2*)(ffn + (size_t)c * ND))[t];
    a.x = a.x * arn + fv.x;
    a.y = a.y * arn + fv.y;
    float ssqB = block_reduce_sum8(a.x * a.x + a.y * a.y, red, w, lane);
    float brn = rsqrtf(ssqB);

    float2 iv = ((const float2*)img)[t];
    float dp = block_reduce_sum8(a.x * iv.x + a.y * iv.y, red, w, lane);

    if (t == 0) logits[c] = expf(lsp[0]) * dp * brn;
}

// Kernel 4: softmax over 1000 logits
__global__ __launch_bounds__(256) void softmax_kernel(const float* __restrict__ logits,
                                                      float* __restrict__ out) {
    __shared__ float red[8];
    int t = threadIdx.x, w = t >> 6, lane = t & 63;
    float l[4];
#pragma unroll
    for (int i = 0; i < 4; ++i) {
        int idx = t * 4 + i;
        l[i] = (idx < NC) ? logits[idx] : -3.402823466e+38f;
    }
    float mx = fmaxf(fmaxf(l[0], l[1]), fmaxf(l[2], l[3]));
#pragma unroll
    for (int off = 32; off >= 1; off >>= 1) mx = fmaxf(mx, __shfl_xor(mx, off, 64));
    __syncthreads();
    if (lane == 0) red[w] = mx;
    __syncthreads();
    mx = fmaxf(fmaxf(red[0], red[1]), fmaxf(red[2], red[3]));
    __syncthreads();

    float e[4], s = 0.f;
#pragma unroll
    for (int i = 0; i < 4; ++i) {
        int idx = t * 4 + i;
        e[i] = (idx < NC) ? expf(l[i] - mx) : 0.f;
        s += e[i];
    }
    s = block_reduce_sum4(s, red, w, lane);
    float inv = 1.f / s;
#pragma unroll
    for (int i = 0; i < 4; ++i) {
        int idx = t * 4 + i;
        if (idx < NC) out[idx] = e[i] * inv;
    }
}

extern "C" void kernel_launch(void* const* d_in, const int* in_sizes, int n_in,
                              void* d_out, int out_size, void* d_ws, size_t ws_size,
                              hipStream_t stream) {
    const float* img    = (const float*)d_in[0];  // (1,D)
    const float* mem    = (const float*)d_in[1];  // (C,50,D)
    const float* fixedg = (const float*)d_in[2];  // (C,1,D)
    const float* gb     = (const float*)d_in[3];  // (C,D)
    const float* gbk    = (const float*)d_in[4];  // (C,D)
    const float* gbv    = (const float*)d_in[5];  // (C,D)
    const float* ffn    = (const float*)d_in[6];  // (C,D)
    const float* ls     = (const float*)d_in[7];  // scalar

    float* ws      = (float*)d_ws;
    float* qpart   = ws;                   // 40*1024
    float* qn      = ws + 40 * ND;         // 1024
    float* logits  = ws + 41 * ND;         // 1000
    float* out     = (float*)d_out;

    colsum_part<<<40, 256, 0, stream>>>(gb, qpart);
    qnorm_kernel<<<1, 256, 0, stream>>>(img, qpart, qn);
    dualmem_fused<<<NC, 512, 0, stream>>>(mem, fixedg, qn, gbk, gbv, ffn, img, ls, logits);
    softmax_kernel<<<1, 256, 0, stream>>>(logits, out);
}

// Round 3
// 295.746 us; speedup vs baseline: 1.0824x; 1.0237x over previous
//
#include <hip/hip_runtime.h>
#include <math.h>

#define BETA 5.5f
#define NC 1000
#define NM 51
#define ND 1024

typedef float nt_float4 __attribute__((ext_vector_type(4)));

__device__ __forceinline__ float wave_reduce_sum(float v) {
#pragma unroll
    for (int off = 32; off >= 1; off >>= 1) v += __shfl_xor(v, off, 64);
    return v;
}

// 4-wave block reduce (for 256-thread kernels)
__device__ __forceinline__ float block_reduce_sum4(float v, float* red, int w, int lane) {
    v = wave_reduce_sum(v);
    __syncthreads();
    if (lane == 0) red[w] = v;
    __syncthreads();
    return red[0] + red[1] + red[2] + red[3];
}

// 8-wave block reduce (for the 512-thread fused kernel)
__device__ __forceinline__ float block_reduce_sum8(float v, float* red, int w, int lane) {
    v = wave_reduce_sum(v);
    __syncthreads();
    if (lane == 0) red[w] = v;
    __syncthreads();
    return (red[0] + red[1] + red[2] + red[3]) + (red[4] + red[5] + red[6] + red[7]);
}

// Kernel 1: partial column sums of global_bias (C x D) -> qpart[40][D].
__global__ __launch_bounds__(256) void colsum_part(const float* __restrict__ gb,
                                                   float* __restrict__ qpart) {
    const int t = threadIdx.x;
    const float4* p = (const float4*)(gb + (size_t)blockIdx.x * 25 * ND) + t;
    float4 s = make_float4(0.f, 0.f, 0.f, 0.f);
#pragma unroll
    for (int c = 0; c < 25; ++c) {
        float4 v = p[c * (ND / 4)];
        s.x += v.x; s.y += v.y; s.z += v.z; s.w += v.w;
    }
    ((float4*)qpart)[blockIdx.x * (ND / 4) + t] = s;
}

// Kernel 2: qn = l2norm(img + colsum/NC). One block; final normalized query.
__global__ __launch_bounds__(256) void qnorm_kernel(const float* __restrict__ img,
                                                    const float* __restrict__ qpart,
                                                    float* __restrict__ qn) {
    __shared__ float red[8];
    const int t = threadIdx.x, w = t >> 6, lane = t & 63;
    float4 s = make_float4(0.f, 0.f, 0.f, 0.f);
#pragma unroll
    for (int p = 0; p < 40; ++p) {
        float4 v = ((const float4*)qpart)[p * (ND / 4) + t];
        s.x += v.x; s.y += v.y; s.z += v.z; s.w += v.w;
    }
    float4 iv = ((const float4*)img)[t];
    float4 q;
    q.x = iv.x + s.x * (1.f / NC);
    q.y = iv.y + s.y * (1.f / NC);
    q.z = iv.z + s.z * (1.f / NC);
    q.w = iv.w + s.w * (1.f / NC);
    float ssq = block_reduce_sum4(q.x * q.x + q.y * q.y + q.z * q.z + q.w * q.w, red, w, lane);
    float r = rsqrtf(ssq);
    float4 o = make_float4(q.x * r, q.y * r, q.z * r, q.w * r);
    ((float4*)qn)[t] = o;
}

__device__ __forceinline__ const nt_float4* row_ptr(const float* __restrict__ mem,
                                                    const float* __restrict__ fixedg,
                                                    int c, int m) {
    return (m < 50) ? (const nt_float4*)(mem + ((size_t)c * 50 + m) * ND)
                    : (const nt_float4*)(fixedg + (size_t)c * ND);
}

// Kernel 3 (fused main+finalize): one class per 512-thread block (8 waves).
// Wave w owns rows w, w+8, ... . NEW: a 256B-per-row probe phase detects empty
// (all-zero) rows via __any ballot, building a wave-uniform bitmask; the
// software-pipelined full-row loop then streams ONLY non-empty rows
// (~25 of 50 mem rows are zero -> ~100 MB of HBM reads skipped). Rows are
// walked via ctz on the bitmask (no runtime-indexed arrays -> no scratch).
__global__ __launch_bounds__(512) void dualmem_fused(
    const float* __restrict__ mem,     // (C,50,D)
    const float* __restrict__ fixedg,  // (C,1,D)
    const float* __restrict__ qn_g,    // (D) normalized query
    const float* __restrict__ gbk,     // (C,D)
    const float* __restrict__ gbv,     // (C,D)
    const float* __restrict__ ffn,     // (C,D)
    const float* __restrict__ img,     // (1,D)
    const float* __restrict__ lsp,     // scalar
    float* __restrict__ logits)        // (C)
{
    __shared__ float lds_acc[8 * ND];  // 32 KB per-wave partials
    __shared__ float red[8];

    const int c = blockIdx.x;
    const int t = threadIdx.x;
    const int w = t >> 6;
    const int lane = t & 63;

    // ---- probe phase: 1 dword/lane (256B) per owned row, ballot emptiness ----
    float pr[7];
#pragma unroll
    for (int k = 0; k < 7; ++k) {
        const int m = w + 8 * k;
        if (m < NM) {
            const float* r = (const float*)row_ptr(mem, fixedg, c, m);
            pr[k] = r[lane];
        } else {
            pr[k] = 0.f;
        }
    }
    unsigned rmask = 0;
#pragma unroll
    for (int k = 0; k < 7; ++k) {
        if (__any(pr[k] != 0.f)) rmask |= 1u << k;  // wave-uniform
    }

    // ---- per-wave copies: normalized q + per-class biases ----
    float4 qn[4], bk[4], bv[4], acc[4];
    const float* bkp = gbk + (size_t)c * ND;
    const float* bvp = gbv + (size_t)c * ND;
#pragma unroll
    for (int j = 0; j < 4; ++j) {
        qn[j] = ((const float4*)qn_g)[j * 64 + lane];
        bk[j] = ((const float4*)bkp)[j * 64 + lane];
        bv[j] = ((const float4*)bvp)[j * 64 + lane];
        acc[j] = make_float4(0.f, 0.f, 0.f, 0.f);
    }

    // ---- software-pipelined loop over NON-EMPTY rows only ----
    if (rmask) {
        nt_float4 cur[4], nxt[4];
        {
            const int m0 = w + 8 * __builtin_ctz(rmask);
            const nt_float4* r = row_ptr(mem, fixedg, c, m0);
#pragma unroll
            for (int j = 0; j < 4; ++j) cur[j] = __builtin_nontemporal_load(&r[j * 64 + lane]);
        }
        unsigned rest = rmask & (rmask - 1);  // rows after the current one

        while (true) {
            if (rest) {  // prefetch next non-empty row while reducing this one
                const int mn = w + 8 * __builtin_ctz(rest);
                const nt_float4* r = row_ptr(mem, fixedg, c, mn);
#pragma unroll
                for (int j = 0; j < 4; ++j) nxt[j] = __builtin_nontemporal_load(&r[j * 64 + lane]);
            }

            float ssqK = 0.f, dotK = 0.f, ssqV = 0.f;
#pragma unroll
            for (int j = 0; j < 4; ++j) {
                nt_float4 v = cur[j];
                float kx = v.x + bk[j].x, ky = v.y + bk[j].y, kz = v.z + bk[j].z, kw = v.w + bk[j].w;
                ssqK += kx * kx + ky * ky + kz * kz + kw * kw;
                dotK += qn[j].x * kx + qn[j].y * ky + qn[j].z * kz + qn[j].w * kw;
                float vx = v.x + bv[j].x, vy = v.y + bv[j].y, vz = v.z + bv[j].z, vw = v.w + bv[j].w;
                ssqV += vx * vx + vy * vy + vz * vz + vw * vw;
            }
            ssqK = wave_reduce_sum(ssqK);
            dotK = wave_reduce_sum(dotK);
            ssqV = wave_reduce_sum(ssqV);

            float simv = expf(-BETA * (1.f - dotK * rsqrtf(ssqK)));
            float wt = simv * rsqrtf(ssqV);
#pragma unroll
            for (int j = 0; j < 4; ++j) {
                acc[j].x += wt * (cur[j].x + bv[j].x);
                acc[j].y += wt * (cur[j].y + bv[j].y);
                acc[j].z += wt * (cur[j].z + bv[j].z);
                acc[j].w += wt * (cur[j].w + bv[j].w);
            }

            if (!rest) break;
            rest &= rest - 1;
#pragma unroll
            for (int j = 0; j < 4; ++j) cur[j] = nxt[j];
        }
    }

    // ---- combine 8 waves through LDS ----
#pragma unroll
    for (int j = 0; j < 4; ++j)
        ((float4*)lds_acc)[w * 256 + j * 64 + lane] = acc[j];
    __syncthreads();

    // each of the 512 threads owns one float2 slice (1024 floats total)
    float2 s0 = make_float2(0.f, 0.f), s1 = make_float2(0.f, 0.f);
#pragma unroll
    for (int wv = 0; wv < 4; ++wv) {
        float2 p = ((const float2*)lds_acc)[wv * 512 + t];
        s0.x += p.x; s0.y += p.y;
    }
#pragma unroll
    for (int wv = 4; wv < 8; ++wv) {
        float2 p = ((const float2*)lds_acc)[wv * 512 + t];
        s1.x += p.x; s1.y += p.y;
    }
    float2 a = make_float2(s0.x + s1.x, s0.y + s1.y);

    // ---- finalize: l2norm -> +ffn -> l2norm -> logit ----
    float ssqA = block_reduce_sum8(a.x * a.x + a.y * a.y, red, w, lane);
    float arn = rsqrtf(ssqA);
    float2 fv = ((const float2*)(ffn + (size_t)c * ND))[t];
    a.x = a.x * arn + fv.x;
    a.y = a.y * arn + fv.y;
    float ssqB = block_reduce_sum8(a.x * a.x + a.y * a.y, red, w, lane);
    float brn = rsqrtf(ssqB);

    float2 iv = ((const float2*)img)[t];
    float dp = block_reduce_sum8(a.x * iv.x + a.y * iv.y, red, w, lane);

    if (t == 0) logits[c] = expf(lsp[0]) * dp * brn;
}

// Kernel 4: softmax over 1000 logits
__global__ __launch_bounds__(256) void softmax_kernel(const float* __restrict__ logits,
                                                      float* __restrict__ out) {
    __shared__ float red[8];
    int t = threadIdx.x, w = t >> 6, lane = t & 63;
    float l[4];
#pragma unroll
    for (int i = 0; i < 4; ++i) {
        int idx = t * 4 + i;
        l[i] = (idx < NC) ? logits[idx] : -3.402823466e+38f;
    }
    float mx = fmaxf(fmaxf(l[0], l[1]), fmaxf(l[2], l[3]));
#pragma unroll
    for (int off = 32; off >= 1; off >>= 1) mx = fmaxf(mx, __shfl_xor(mx, off, 64));
    __syncthreads();
    if (lane == 0) red[w] = mx;
    __syncthreads();
    mx = fmaxf(fmaxf(red[0], red[1]), fmaxf(red[2], red[3]));
    __syncthreads();

    float e[4], s = 0.f;
#pragma unroll
    for (int i = 0; i < 4; ++i) {
        int idx = t * 4 + i;
        e[i] = (idx < NC) ? expf(l[i] - mx) : 0.f;
        s += e[i];
    }
    s = block_reduce_sum4(s, red, w, lane);
    float inv = 1.f / s;
#pragma unroll
    for (int i = 0; i < 4; ++i) {
        int idx = t * 4 + i;
        if (idx < NC) out[idx] = e[i] * inv;
    }
}

extern "C" void kernel_launch(void* const* d_in, const int* in_sizes, int n_in,
                              void* d_out, int out_size, void* d_ws, size_t ws_size,
                              hipStream_t stream) {
    const float* img    = (const float*)d_in[0];  // (1,D)
    const float* mem    = (const float*)d_in[1];  // (C,50,D)
    const float* fixedg = (const float*)d_in[2];  // (C,1,D)
    const float* gb     = (const float*)d_in[3];  // (C,D)
    const float* gbk    = (const float*)d_in[4];  // (C,D)
    const float* gbv    = (const float*)d_in[5];  // (C,D)
    const float* ffn    = (const float*)d_in[6];  // (C,D)
    const float* ls     = (const float*)d_in[7];  // scalar

    float* ws      = (float*)d_ws;
    float* qpart   = ws;                   // 40*1024
    float* qn      = ws + 40 * ND;         // 1024
    float* logits  = ws + 41 * ND;         // 1000
    float* out     = (float*)d_out;

    colsum_part<<<40, 256, 0, stream>>>(gb, qpart);
    qnorm_kernel<<<1, 256, 0, stream>>>(img, qpart, qn);
    dualmem_fused<<<NC, 512, 0, stream>>>(mem, fixedg, qn, gbk, gbv, ffn, img, ls, logits);
    softmax_kernel<<<1, 256, 0, stream>>>(logits, out);
}

// Round 4
// 291.796 us; speedup vs baseline: 1.0971x; 1.0135x over previous
//
#include <hip/hip_runtime.h>
#include <math.h>

#define BETA 5.5f
#define NC 1000
#define NM 51
#define ND 1024

typedef float nt_float4 __attribute__((ext_vector_type(4)));

__device__ __forceinline__ float wave_reduce_sum(float v) {
#pragma unroll
    for (int off = 32; off >= 1; off >>= 1) v += __shfl_xor(v, off, 64);
    return v;
}

// 4-wave block reduce (256-thread kernels)
__device__ __forceinline__ float block_reduce_sum4(float v, float* red, int w, int lane) {
    v = wave_reduce_sum(v);
    __syncthreads();
    if (lane == 0) red[w] = v;
    __syncthreads();
    return red[0] + red[1] + red[2] + red[3];
}

// Kernel 1: partial column sums of global_bias (C x D) -> qpart[40][D].
__global__ __launch_bounds__(256) void colsum_part(const float* __restrict__ gb,
                                                   float* __restrict__ qpart) {
    const int t = threadIdx.x;
    const float4* p = (const float4*)(gb + (size_t)blockIdx.x * 25 * ND) + t;
    float4 s = make_float4(0.f, 0.f, 0.f, 0.f);
#pragma unroll
    for (int c = 0; c < 25; ++c) {
        float4 v = p[c * (ND / 4)];
        s.x += v.x; s.y += v.y; s.z += v.z; s.w += v.w;
    }
    ((float4*)qpart)[blockIdx.x * (ND / 4) + t] = s;
}

// Kernel 2: qn = l2norm(img + colsum/NC). One block; final normalized query.
__global__ __launch_bounds__(256) void qnorm_kernel(const float* __restrict__ img,
                                                    const float* __restrict__ qpart,
                                                    float* __restrict__ qn) {
    __shared__ float red[8];
    const int t = threadIdx.x, w = t >> 6, lane = t & 63;
    float4 s = make_float4(0.f, 0.f, 0.f, 0.f);
#pragma unroll
    for (int p = 0; p < 40; ++p) {
        float4 v = ((const float4*)qpart)[p * (ND / 4) + t];
        s.x += v.x; s.y += v.y; s.z += v.z; s.w += v.w;
    }
    float4 iv = ((const float4*)img)[t];
    float4 q;
    q.x = iv.x + s.x * (1.f / NC);
    q.y = iv.y + s.y * (1.f / NC);
    q.z = iv.z + s.z * (1.f / NC);
    q.w = iv.w + s.w * (1.f / NC);
    float ssq = block_reduce_sum4(q.x * q.x + q.y * q.y + q.z * q.z + q.w * q.w, red, w, lane);
    float r = rsqrtf(ssq);
    float4 o = make_float4(q.x * r, q.y * r, q.z * r, q.w * r);
    ((float4*)qn)[t] = o;
}

__device__ __forceinline__ const nt_float4* row_ptr(const float* __restrict__ mem,
                                                    const float* __restrict__ fixedg,
                                                    int c, int m) {
    return (m < 50) ? (const nt_float4*)(mem + ((size_t)c * 50 + m) * ND)
                    : (const nt_float4*)(fixedg + (size_t)c * ND);
}

// Kernel 3 (fused main+finalize): one class per 256-thread block (4 waves).
// vs the 8-wave version: per-class fixed costs (qn/bias load replication, LDS
// combine depth, probe count amortization) halve, each wave owns ~6 non-empty
// rows (deeper pipeline amortization), and the finalize fuses the second-norm
// and img-dot reductions into a single barrier pair.
__global__ __launch_bounds__(256) void dualmem_fused(
    const float* __restrict__ mem,     // (C,50,D)
    const float* __restrict__ fixedg,  // (C,1,D)
    const float* __restrict__ qn_g,    // (D) normalized query
    const float* __restrict__ gbk,     // (C,D)
    const float* __restrict__ gbv,     // (C,D)
    const float* __restrict__ ffn,     // (C,D)
    const float* __restrict__ img,     // (1,D)
    const float* __restrict__ lsp,     // scalar
    float* __restrict__ logits)        // (C)
{
    __shared__ float lds_acc[4 * ND];  // 16 KB per-wave partials
    __shared__ float red[8];

    const int c = blockIdx.x;
    const int t = threadIdx.x;
    const int w = t >> 6;
    const int lane = t & 63;

    // ---- probe phase: 1 dword/lane (256B) per owned row (w, w+4, ...) ----
    float pr[13];
#pragma unroll
    for (int k = 0; k < 13; ++k) {
        const int m = w + 4 * k;
        if (m < NM) {
            const float* r = (const float*)row_ptr(mem, fixedg, c, m);
            pr[k] = r[lane];
        } else {
            pr[k] = 0.f;
        }
    }

    // ---- per-wave copies: normalized q + per-class biases (independent of probe) ----
    float4 qn[4], bk[4], bv[4], acc[4];
    const float* bkp = gbk + (size_t)c * ND;
    const float* bvp = gbv + (size_t)c * ND;
#pragma unroll
    for (int j = 0; j < 4; ++j) {
        qn[j] = ((const float4*)qn_g)[j * 64 + lane];
        bk[j] = ((const float4*)bkp)[j * 64 + lane];
        bv[j] = ((const float4*)bvp)[j * 64 + lane];
        acc[j] = make_float4(0.f, 0.f, 0.f, 0.f);
    }

    unsigned rmask = 0;
#pragma unroll
    for (int k = 0; k < 13; ++k) {
        if (__any(pr[k] != 0.f)) rmask |= 1u << k;  // wave-uniform
    }

    // ---- software-pipelined loop over NON-EMPTY rows only ----
    if (rmask) {
        nt_float4 cur[4], nxt[4];
        {
            const int m0 = w + 4 * __builtin_ctz(rmask);
            const nt_float4* r = row_ptr(mem, fixedg, c, m0);
#pragma unroll
            for (int j = 0; j < 4; ++j) cur[j] = __builtin_nontemporal_load(&r[j * 64 + lane]);
        }
        unsigned rest = rmask & (rmask - 1);  // rows after the current one

        while (true) {
            if (rest) {  // prefetch next non-empty row while reducing this one
                const int mn = w + 4 * __builtin_ctz(rest);
                const nt_float4* r = row_ptr(mem, fixedg, c, mn);
#pragma unroll
                for (int j = 0; j < 4; ++j) nxt[j] = __builtin_nontemporal_load(&r[j * 64 + lane]);
            }

            float ssqK = 0.f, dotK = 0.f, ssqV = 0.f;
#pragma unroll
            for (int j = 0; j < 4; ++j) {
                nt_float4 v = cur[j];
                float kx = v.x + bk[j].x, ky = v.y + bk[j].y, kz = v.z + bk[j].z, kw = v.w + bk[j].w;
                ssqK += kx * kx + ky * ky + kz * kz + kw * kw;
                dotK += qn[j].x * kx + qn[j].y * ky + qn[j].z * kz + qn[j].w * kw;
                float vx = v.x + bv[j].x, vy = v.y + bv[j].y, vz = v.z + bv[j].z, vw = v.w + bv[j].w;
                ssqV += vx * vx + vy * vy + vz * vz + vw * vw;
            }
            ssqK = wave_reduce_sum(ssqK);
            dotK = wave_reduce_sum(dotK);
            ssqV = wave_reduce_sum(ssqV);

            float simv = expf(-BETA * (1.f - dotK * rsqrtf(ssqK)));
            float wt = simv * rsqrtf(ssqV);
#pragma unroll
            for (int j = 0; j < 4; ++j) {
                acc[j].x += wt * (cur[j].x + bv[j].x);
                acc[j].y += wt * (cur[j].y + bv[j].y);
                acc[j].z += wt * (cur[j].z + bv[j].z);
                acc[j].w += wt * (cur[j].w + bv[j].w);
            }

            if (!rest) break;
            rest &= rest - 1;
#pragma unroll
            for (int j = 0; j < 4; ++j) cur[j] = nxt[j];
        }
    }

    // ---- combine 4 waves through LDS ----
#pragma unroll
    for (int j = 0; j < 4; ++j)
        ((float4*)lds_acc)[w * 256 + j * 64 + lane] = acc[j];
    __syncthreads();

    // each of the 256 threads owns one float4 slice (1024 floats total)
    float4 a = make_float4(0.f, 0.f, 0.f, 0.f);
#pragma unroll
    for (int wv = 0; wv < 4; ++wv) {
        float4 p = ((const float4*)lds_acc)[wv * 256 + t];
        a.x += p.x; a.y += p.y; a.z += p.z; a.w += p.w;
    }

    // ---- finalize: l2norm -> +ffn -> l2norm & img-dot (fused reduce) -> logit ----
    float ssqA = block_reduce_sum4(a.x * a.x + a.y * a.y + a.z * a.z + a.w * a.w, red, w, lane);
    float arn = rsqrtf(ssqA);
    float4 fv = ((const float4*)(ffn + (size_t)c * ND))[t];
    a.x = a.x * arn + fv.x;
    a.y = a.y * arn + fv.y;
    a.z = a.z * arn + fv.z;
    a.w = a.w * arn + fv.w;

    float4 iv = ((const float4*)img)[t];
    float bb = a.x * a.x + a.y * a.y + a.z * a.z + a.w * a.w;
    float dd = a.x * iv.x + a.y * iv.y + a.z * iv.z + a.w * iv.w;
    bb = wave_reduce_sum(bb);
    dd = wave_reduce_sum(dd);
    __syncthreads();
    if (lane == 0) { red[w] = bb; red[4 + w] = dd; }
    __syncthreads();
    float ssqB = red[0] + red[1] + red[2] + red[3];
    float dp   = red[4] + red[5] + red[6] + red[7];

    if (t == 0) logits[c] = expf(lsp[0]) * dp * rsqrtf(ssqB);
}

// Kernel 4: softmax over 1000 logits
__global__ __launch_bounds__(256) void softmax_kernel(const float* __restrict__ logits,
                                                      float* __restrict__ out) {
    __shared__ float red[8];
    int t = threadIdx.x, w = t >> 6, lane = t & 63;
    float l[4];
#pragma unroll
    for (int i = 0; i < 4; ++i) {
        int idx = t * 4 + i;
        l[i] = (idx < NC) ? logits[idx] : -3.402823466e+38f;
    }
    float mx = fmaxf(fmaxf(l[0], l[1]), fmaxf(l[2], l[3]));
#pragma unroll
    for (int off = 32; off >= 1; off >>= 1) mx = fmaxf(mx, __shfl_xor(mx, off, 64));
    __syncthreads();
    if (lane == 0) red[w] = mx;
    __syncthreads();
    mx = fmaxf(fmaxf(red[0], red[1]), fmaxf(red[2], red[3]));
    __syncthreads();

    float e[4], s = 0.f;
#pragma unroll
    for (int i = 0; i < 4; ++i) {
        int idx = t * 4 + i;
        e[i] = (idx < NC) ? expf(l[i] - mx) : 0.f;
        s += e[i];
    }
    s = block_reduce_sum4(s, red, w, lane);
    float inv = 1.f / s;
#pragma unroll
    for (int i = 0; i < 4; ++i) {
        int idx = t * 4 + i;
        if (idx < NC) out[idx] = e[i] * inv;
    }
}

extern "C" void kernel_launch(void* const* d_in, const int* in_sizes, int n_in,
                              void* d_out, int out_size, void* d_ws, size_t ws_size,
                              hipStream_t stream) {
    const float* img    = (const float*)d_in[0];  // (1,D)
    const float* mem    = (const float*)d_in[1];  // (C,50,D)
    const float* fixedg = (const float*)d_in[2];  // (C,1,D)
    const float* gb     = (const float*)d_in[3];  // (C,D)
    const float* gbk    = (const float*)d_in[4];  // (C,D)
    const float* gbv    = (const float*)d_in[5];  // (C,D)
    const float* ffn    = (const float*)d_in[6];  // (C,D)
    const float* ls     = (const float*)d_in[7];  // scalar

    float* ws      = (float*)d_ws;
    float* qpart   = ws;                   // 40*1024
    float* qn      = ws + 40 * ND;         // 1024
    float* logits  = ws + 41 * ND;         // 1000
    float* out     = (float*)d_out;

    colsum_part<<<40, 256, 0, stream>>>(gb, qpart);
    qnorm_kernel<<<1, 256, 0, stream>>>(img, qpart, qn);
    dualmem_fused<<<NC, 256, 0, stream>>>(mem, fixedg, qn, gbk, gbv, ffn, img, ls, logits);
    softmax_kernel<<<1, 256, 0, stream>>>(logits, out);
}